// Round 6
// baseline (6193.047 us; speedup 1.0000x reference)
//
#include <hip/hip_runtime.h>
#include <stdint.h>

#define B_    256
#define T_    1024
#define H_    512
#define NIN_  64
#define NOUT_ 64

// rnn_scan: 64 blocks = 16 batch-groups x 4 column-splits.
// Block (gi,s): 16 batch rows, 128 cols. W slice = 128KB -> 32 units/wave,
// all register-resident. Per-step cross-block h-exchange via L3 atomics.
#define GRP   16
#define SPL   4
#define BBLK  16
#define SC_NW 4

typedef __attribute__((ext_vector_type(8))) short bf16x8;
typedef __attribute__((ext_vector_type(4))) float f32x4;
typedef __attribute__((ext_vector_type(4))) uint32_t u32x4;

__device__ __forceinline__ short f2bf(float f) {
  uint32_t u = __float_as_uint(f);
  uint32_t r = (u + 0x7FFFu + ((u >> 16) & 1u)) >> 16;
  return (short)(r & 0xFFFFu);
}

__device__ __forceinline__ bf16x8 pack8(float4 lo, float4 hi) {
  bf16x8 s;
  s[0] = f2bf(lo.x); s[1] = f2bf(lo.y); s[2] = f2bf(lo.z); s[3] = f2bf(lo.w);
  s[4] = f2bf(hi.x); s[5] = f2bf(hi.y); s[6] = f2bf(hi.z); s[7] = f2bf(hi.w);
  return s;
}

// interleaved pack for the k-permuted fragment order: (lo0,hi0,lo1,hi1,...)
__device__ __forceinline__ bf16x8 pack8i(float4 lo, float4 hi) {
  bf16x8 s;
  s[0] = f2bf(lo.x); s[1] = f2bf(hi.x);
  s[2] = f2bf(lo.y); s[3] = f2bf(hi.y);
  s[4] = f2bf(lo.z); s[5] = f2bf(hi.z);
  s[6] = f2bf(lo.w); s[7] = f2bf(hi.w);
  return s;
}

__device__ __forceinline__ float fast_tanh(float x) {
  float e = __expf(2.0f * x);
  return 1.0f - __fdividef(2.0f, e + 1.0f);
}

// ---------------------------------------------------------------------------
// xproj: inp[b,t,h] = X[b,t,:] @ Win[h,:]  (f32, written into hid region)
// ---------------------------------------------------------------------------
#define XP_BLOCKS 512
__global__ __launch_bounds__(512, 2) void xproj(
    const float* __restrict__ X, const float* __restrict__ Win,
    float* __restrict__ inp)
{
  const int tid  = threadIdx.x;
  const int lane = tid & 63;
  const int w    = tid >> 6;
  const int g    = lane >> 4;
  const int m    = lane & 15;

  bf16x8 Bf[2][4];
#pragma unroll
  for (int kb = 0; kb < 2; ++kb)
#pragma unroll
    for (int jt = 0; jt < 4; ++jt) {
      const int j = 64 * w + 16 * jt + m;
      const float4* p = reinterpret_cast<const float4*>(Win + (size_t)j * NIN_ + 32 * kb + 8 * g);
      Bf[kb][jt] = pack8(p[0], p[1]);
    }

  const int NTILES = (B_ * T_) / 16;
  const f32x4 zero = {0.f, 0.f, 0.f, 0.f};

  for (int tile = blockIdx.x; tile < NTILES; tile += XP_BLOCKS) {
    const size_t row0 = (size_t)tile * 16;
    f32x4 acc[4];
    {
      const float4* p = reinterpret_cast<const float4*>(X + (row0 + m) * NIN_ + 8 * g);
      const bf16x8 a = pack8(p[0], p[1]);
#pragma unroll
      for (int jt = 0; jt < 4; ++jt)
        acc[jt] = __builtin_amdgcn_mfma_f32_16x16x32_bf16(a, Bf[0][jt], zero, 0, 0, 0);
    }
    {
      const float4* p = reinterpret_cast<const float4*>(X + (row0 + m) * NIN_ + 32 + 8 * g);
      const bf16x8 a = pack8(p[0], p[1]);
#pragma unroll
      for (int jt = 0; jt < 4; ++jt)
        acc[jt] = __builtin_amdgcn_mfma_f32_16x16x32_bf16(a, Bf[1][jt], acc[jt], 0, 0, 0);
    }
#pragma unroll
    for (int jt = 0; jt < 4; ++jt)
#pragma unroll
      for (int r = 0; r < 4; ++r)
        inp[(row0 + 4 * g + r) * H_ + 64 * w + 16 * jt + m] = acc[jt][r];
  }
}

// ---------------------------------------------------------------------------
// rnn_scan: persistent, column-split with per-step h-exchange.
//   hbuf u32 layout: [buf][kb][mrow][16 pairs]; pair q of (kb,mrow) packs
//   bf16(k=q) | bf16(k=16+q)<<16.  A-frag read = dense conflict-free b128.
//   B-frags loaded with matching k-interleave (pack8i).
// ---------------------------------------------------------------------------
__global__ __launch_bounds__(SC_NW * 64, 1) void rnn_scan(
    const float* __restrict__ h0, const float* __restrict__ W,
    float* __restrict__ hid, uint32_t* __restrict__ exch,
    uint32_t* __restrict__ flag)
{
  __shared__ uint32_t hbuf[2][16][16][16];   // 32 KB

  const int tid  = threadIdx.x;
  const int lane = tid & 63;
  const int w    = tid >> 6;    // wave 0..3
  const int g    = lane >> 4;
  const int m    = lane & 15;
  const int bid  = blockIdx.x;
  const int s    = bid & 3;     // column split 0..3
  const int gi   = bid >> 2;    // batch group 0..15
  const int b0   = gi * BBLK;
  const int c0   = s * 128 + 32 * w;   // this wave's first col
  const int mykb = 4 * s + w;          // the kb this wave's cols constitute

  // --- B-fragments: 16 kb x 2 jt, k-interleaved; 128 VGPRs
  bf16x8 Wf[16][2];
#pragma unroll
  for (int kb = 0; kb < 16; ++kb)
#pragma unroll
    for (int jt = 0; jt < 2; ++jt) {
      const int col = c0 + 16 * jt + m;
      const float4* plo = reinterpret_cast<const float4*>(W + (size_t)col * H_ + 32 * kb + 4 * g);
      const float4* phi = reinterpret_cast<const float4*>(W + (size_t)col * H_ + 32 * kb + 16 + 4 * g);
      Wf[kb][jt] = pack8i(plo[0], phi[0]);
    }

  // --- prologue: hbuf[0] = tanh(h0) in pair layout (all 16 kb)
#pragma unroll
  for (int i = 0; i < 16; ++i) {
    const int c  = tid + 256 * i;     // < 4096
    const int kb = c >> 8;
    const int mr = (c >> 4) & 15;
    const int q  = c & 15;
    const float lo = fast_tanh(h0[(size_t)(b0 + mr) * H_ + 32 * kb + q]);
    const float hi = fast_tanh(h0[(size_t)(b0 + mr) * H_ + 32 * kb + 16 + q]);
    hbuf[0][kb][mr][q] = (uint32_t)(uint16_t)f2bf(lo) | ((uint32_t)(uint16_t)f2bf(hi) << 16);
  }

  // --- inp_cur for t=0: lane owns (rows 4g+r, cols c0+16jt+m)
  float inp_cur[2][4];
#pragma unroll
  for (int jt = 0; jt < 2; ++jt)
#pragma unroll
    for (int r = 0; r < 4; ++r)
      inp_cur[jt][r] = hid[((size_t)(b0 + 4 * g + r) * T_ + 0) * H_ + c0 + 16 * jt + m];

  __syncthreads();

  const f32x4 zero = {0.f, 0.f, 0.f, 0.f};
  int cur = 0;

#pragma clang loop unroll(disable)
  for (int t = 0; t < T_; ++t) {
    const int nxt = cur ^ 1;
    const int par = t & 1;
    const bool last = (t + 1 == T_);

    // inp prefetch for t+1
    float inp_nxt[2][4] = {{0.f,0.f,0.f,0.f},{0.f,0.f,0.f,0.f}};
    if (!last) {
#pragma unroll
      for (int jt = 0; jt < 2; ++jt)
#pragma unroll
        for (int r = 0; r < 4; ++r)
          inp_nxt[jt][r] = hid[((size_t)(b0 + 4 * g + r) * T_ + (t + 1)) * H_ + c0 + 16 * jt + m];
    }

    // MFMA phase: acc[jt] over 16 kb; A from hbuf[cur] (dense b128)
    f32x4 acc[2] = {zero, zero};
#pragma unroll
    for (int kb = 0; kb < 16; ++kb) {
      const bf16x8 a = *reinterpret_cast<const bf16x8*>(&hbuf[cur][kb][m][4 * g]);
      acc[0] = __builtin_amdgcn_mfma_f32_16x16x32_bf16(a, Wf[kb][0], acc[0], 0, 0, 0);
      acc[1] = __builtin_amdgcn_mfma_f32_16x16x32_bf16(a, Wf[kb][1], acc[1], 0, 0, 0);
    }

    // epilogue: lane directly owns rows 4g+r, cols c0+16jt+m
#pragma unroll
    for (int r = 0; r < 4; ++r) {
      const float v0 = acc[0][r] + inp_cur[0][r];
      const float v1 = acc[1][r] + inp_cur[1][r];
      const size_t ho = ((size_t)(b0 + 4 * g + r) * T_ + t) * H_ + c0 + m;
      hid[ho]      = v0;
      hid[ho + 16] = v1;
      const uint32_t pr = (uint32_t)(uint16_t)f2bf(fast_tanh(v0))
                        | ((uint32_t)(uint16_t)f2bf(fast_tanh(v1)) << 16);
      hbuf[nxt][mykb][4 * g + r][m] = pr;   // own slice -> LDS
      if (!last)
        __hip_atomic_store(&exch[(((size_t)(par * GRP + gi) * 16 + mykb) * 16 + 4 * g + r) * 16 + m],
                           pr, __ATOMIC_RELAXED, __HIP_MEMORY_SCOPE_AGENT);
    }
#pragma unroll
    for (int jt = 0; jt < 2; ++jt)
#pragma unroll
      for (int r = 0; r < 4; ++r) inp_cur[jt][r] = inp_nxt[jt][r];

    if (!last) {
      __syncthreads();   // all exch stores drained (vmcnt0 at barrier)
      if (tid == 0)
        __hip_atomic_store(&flag[bid], (uint32_t)(t + 1),
                           __ATOMIC_RELEASE, __HIP_MEMORY_SCOPE_AGENT);
      if (tid < 3) {
        const int ps   = tid + (tid >= s ? 1 : 0);
        const int pbid = (gi << 2) + ps;
        while (__hip_atomic_load(&flag[pbid], __ATOMIC_ACQUIRE,
                                 __HIP_MEMORY_SCOPE_AGENT) < (uint32_t)(t + 1))
          __builtin_amdgcn_s_sleep(1);
      }
      __syncthreads();

      // stage 12 partner kbs (12KB): 12 u32 atomic loads -> 3 ds_write_b128
      {
        const int cb = tid * 12;
        uint32_t v[12];
#pragma unroll
        for (int j = 0; j < 12; ++j) {
          const int c   = cb + j;
          const int kbi = c >> 8;
          const int rem = c & 255;
          const int kb  = kbi + (kbi >= 4 * s ? 4 : 0);
          v[j] = __hip_atomic_load(
              &exch[(((size_t)(par * GRP + gi) * 16 + kb) * 16 + (rem >> 4)) * 16 + (rem & 15)],
              __ATOMIC_RELAXED, __HIP_MEMORY_SCOPE_AGENT);
        }
#pragma unroll
        for (int ch = 0; ch < 3; ++ch) {
          const int c   = cb + ch * 4;
          const int kbi = c >> 8;
          const int rem = c & 255;
          const int kb  = kbi + (kbi >= 4 * s ? 4 : 0);
          u32x4 q; q[0] = v[ch*4]; q[1] = v[ch*4+1]; q[2] = v[ch*4+2]; q[3] = v[ch*4+3];
          *reinterpret_cast<u32x4*>(&hbuf[nxt][kb][rem >> 4][rem & 15]) = q;
        }
      }
      __syncthreads();   // hbuf[nxt] complete
    }
    cur = nxt;
  }
}

// ---------------------------------------------------------------------------
// out = hidden @ W_out^T : memory-bound [BT,512]x[512,64] MFMA GEMM.
// ---------------------------------------------------------------------------
#define OP_BLOCKS 1024
#define OP_WAVES  8
__global__ __launch_bounds__(OP_WAVES * 64, 2) void out_proj(
    const float* __restrict__ hid, const float* __restrict__ Wout,
    float* __restrict__ out)
{
  __shared__ __align__(16) short ws[16][NOUT_][32];   // 64 KB

  const int tid  = threadIdx.x;
  const int lane = tid & 63;
  const int w    = tid >> 6;
  const int g    = lane >> 4;
  const int m    = lane & 15;

#pragma unroll
  for (int i = 0; i < 8; ++i) {
    const int c   = tid + OP_WAVES * 64 * i;
    const int kb  = c >> 8;
    const int col = (c >> 2) & 63;
    const int q   = (c & 3) * 8;
    const float4* p = reinterpret_cast<const float4*>(Wout + (size_t)col * H_ + 32 * kb + q);
    *reinterpret_cast<bf16x8*>(&ws[kb][col][q]) = pack8(p[0], p[1]);
  }
  __syncthreads();

  const int wave_id = blockIdx.x * OP_WAVES + w;
  const int NWAVES  = OP_BLOCKS * OP_WAVES;
  const int NTILES  = (B_ * T_) / 16;

  for (int tile = wave_id; tile < NTILES; tile += NWAVES) {
    const size_t row0 = (size_t)tile * 16;
    f32x4 acc[4];
    {
      const float4* p = reinterpret_cast<const float4*>(hid + (row0 + m) * H_ + 8 * g);
      const bf16x8 a = pack8(p[0], p[1]);
      const f32x4 zero = {0.f, 0.f, 0.f, 0.f};
#pragma unroll
      for (int jt = 0; jt < 4; ++jt) {
        const bf16x8 b = *reinterpret_cast<const bf16x8*>(&ws[0][16 * jt + m][8 * g]);
        acc[jt] = __builtin_amdgcn_mfma_f32_16x16x32_bf16(a, b, zero, 0, 0, 0);
      }
    }
#pragma unroll
    for (int kb = 1; kb < 16; ++kb) {
      const float4* p = reinterpret_cast<const float4*>(hid + (row0 + m) * H_ + 32 * kb + 8 * g);
      const bf16x8 a = pack8(p[0], p[1]);
#pragma unroll
      for (int jt = 0; jt < 4; ++jt) {
        const bf16x8 b = *reinterpret_cast<const bf16x8*>(&ws[kb][16 * jt + m][8 * g]);
        acc[jt] = __builtin_amdgcn_mfma_f32_16x16x32_bf16(a, b, acc[jt], 0, 0, 0);
      }
    }
#pragma unroll
    for (int jt = 0; jt < 4; ++jt)
#pragma unroll
      for (int r = 0; r < 4; ++r)
        out[(row0 + 4 * g + r) * NOUT_ + 16 * jt + m] = acc[jt][r];
  }
}

extern "C" void kernel_launch(void* const* d_in, const int* in_sizes, int n_in,
                              void* d_out, int out_size, void* d_ws, size_t ws_size,
                              hipStream_t stream) {
  const float* X    = (const float*)d_in[0];
  const float* h0   = (const float*)d_in[1];
  const float* W    = (const float*)d_in[2];
  const float* Win  = (const float*)d_in[3];
  const float* Wout = (const float*)d_in[4];

  float* out = (float*)d_out;                                   // [B,T,64]
  float* hid = (float*)d_out + (size_t)B_ * T_ * NOUT_;         // [B,T,512] (inp, then h)

  // exchange buffers + flags live in the tail of the `out` region:
  // out_proj rewrites the whole region afterwards, so this is scratch-safe.
  const size_t out_elems  = (size_t)B_ * T_ * NOUT_;            // 16,777,216 floats
  const size_t exch_u32   = (size_t)2 * GRP * 16 * 16 * 16;     // 131,072
  uint32_t* flag = (uint32_t*)((float*)d_out + out_elems - 64);
  uint32_t* exch = flag - exch_u32;

  hipMemsetAsync(flag, 0, 64 * sizeof(uint32_t), stream);
  xproj<<<dim3(XP_BLOCKS), dim3(512), 0, stream>>>(X, Win, hid);
  rnn_scan<<<dim3(GRP * SPL), dim3(SC_NW * 64), 0, stream>>>(h0, W, hid, exch, flag);
  out_proj<<<dim3(OP_BLOCKS), dim3(OP_WAVES * 64), 0, stream>>>(hid, Wout, out);
}

// Round 7
// 2924.703 us; speedup vs baseline: 2.1175x; 2.1175x over previous
//
#include <hip/hip_runtime.h>
#include <stdint.h>

#define B_    256
#define T_    1024
#define H_    512
#define NIN_  64
#define NOUT_ 64

// rnn_scan: 64 blocks x 8 waves (2 waves/SIMD, 256 regs/wave).
// Wave owns 64 cols (jt 0..3). W per wave: kb 0..9 in regs (40 units, 160 VGPR),
// kb 10..15 streamed from L2 every step (24 units, 2 rotating groups of 4).
// LDS holds only the double-buffered tanh(h) exchange (A-frags).
#define SC_NW   8
#define BBLK    4
#define HROW    528      // hbuf row stride in shorts (1056B -> 8-bank shift/row)
#define KB_REG  10
#define KB_STR  6        // kb 10..15 streamed
#define SW_CHUNKS (SC_NW * KB_STR * 4 * 64)   // 12288 chunks of 16B = 192 KB

typedef __attribute__((ext_vector_type(8))) short bf16x8;
typedef __attribute__((ext_vector_type(4))) float f32x4;

__device__ __forceinline__ short f2bf(float f) {
  uint32_t u = __float_as_uint(f);
  uint32_t r = (u + 0x7FFFu + ((u >> 16) & 1u)) >> 16;
  return (short)(r & 0xFFFFu);
}

__device__ __forceinline__ bf16x8 pack8(float4 lo, float4 hi) {
  bf16x8 s;
  s[0] = f2bf(lo.x); s[1] = f2bf(lo.y); s[2] = f2bf(lo.z); s[3] = f2bf(lo.w);
  s[4] = f2bf(hi.x); s[5] = f2bf(hi.y); s[6] = f2bf(hi.z); s[7] = f2bf(hi.w);
  return s;
}

__device__ __forceinline__ float fast_tanh(float x) {
  float e = __expf(2.0f * x);
  return 1.0f - __fdividef(2.0f, e + 1.0f);
}

// ---------------------------------------------------------------------------
// wprep: pre-convert streamed W (kb 10..15) into per-lane bf16 fragment order.
// chunk c = ((w*6+G)*4 + jt)*64 + lane  ->  16 bytes at sw[c*8].
// ---------------------------------------------------------------------------
__global__ __launch_bounds__(512) void wprep(
    const float* __restrict__ W, short* __restrict__ sw)
{
  const int c = blockIdx.x * 512 + threadIdx.x;
  if (c >= SW_CHUNKS) return;
  const int lane = c & 63;
  const int u    = c >> 6;         // (w*6+G)*4 + jt
  const int jt   = u & 3;
  const int gw   = u >> 2;         // w*6 + G
  const int G    = gw % KB_STR;
  const int w    = gw / KB_STR;
  const int col  = 64 * w + 16 * jt + (lane & 15);
  const int k0   = 32 * (KB_REG + G) + (lane >> 4) * 8;
  const float4* p = reinterpret_cast<const float4*>(W + (size_t)col * H_ + k0);
  *reinterpret_cast<bf16x8*>(sw + (size_t)c * 8) = pack8(p[0], p[1]);
}

// ---------------------------------------------------------------------------
// xproj: inp[b,t,h] = X[b,t,:] @ Win[h,:]  (f32, written into hid region)
// ---------------------------------------------------------------------------
#define XP_BLOCKS 512
__global__ __launch_bounds__(512, 2) void xproj(
    const float* __restrict__ X, const float* __restrict__ Win,
    float* __restrict__ inp)
{
  const int tid  = threadIdx.x;
  const int lane = tid & 63;
  const int w    = tid >> 6;
  const int g    = lane >> 4;
  const int m    = lane & 15;

  bf16x8 Bf[2][4];
#pragma unroll
  for (int kb = 0; kb < 2; ++kb)
#pragma unroll
    for (int jt = 0; jt < 4; ++jt) {
      const int j = 64 * w + 16 * jt + m;
      const float4* p = reinterpret_cast<const float4*>(Win + (size_t)j * NIN_ + 32 * kb + 8 * g);
      Bf[kb][jt] = pack8(p[0], p[1]);
    }

  const int NTILES = (B_ * T_) / 16;
  const f32x4 zero = {0.f, 0.f, 0.f, 0.f};

  for (int tile = blockIdx.x; tile < NTILES; tile += XP_BLOCKS) {
    const size_t row0 = (size_t)tile * 16;
    f32x4 acc[4];
    {
      const float4* p = reinterpret_cast<const float4*>(X + (row0 + m) * NIN_ + 8 * g);
      const bf16x8 a = pack8(p[0], p[1]);
#pragma unroll
      for (int jt = 0; jt < 4; ++jt)
        acc[jt] = __builtin_amdgcn_mfma_f32_16x16x32_bf16(a, Bf[0][jt], zero, 0, 0, 0);
    }
    {
      const float4* p = reinterpret_cast<const float4*>(X + (row0 + m) * NIN_ + 32 + 8 * g);
      const bf16x8 a = pack8(p[0], p[1]);
#pragma unroll
      for (int jt = 0; jt < 4; ++jt)
        acc[jt] = __builtin_amdgcn_mfma_f32_16x16x32_bf16(a, Bf[1][jt], acc[jt], 0, 0, 0);
    }
#pragma unroll
    for (int jt = 0; jt < 4; ++jt)
#pragma unroll
      for (int r = 0; r < 4; ++r)
        inp[(row0 + 4 * g + r) * H_ + 64 * w + 16 * jt + m] = acc[jt][r];
  }
}

// ---------------------------------------------------------------------------
// rnn_scan
// ---------------------------------------------------------------------------
__global__
__attribute__((amdgpu_flat_work_group_size(512, 512), amdgpu_waves_per_eu(2, 2)))
void rnn_scan(
    const float* __restrict__ h0, const float* __restrict__ W,
    float* __restrict__ hid, const short* __restrict__ swbuf)
{
  __shared__ __align__(16) short hbuf[2][BBLK][HROW];   // 16.9 KB

  const int tid  = threadIdx.x;
  const int lane = tid & 63;
  const int w    = tid >> 6;    // wave 0..7
  const int g    = lane >> 4;
  const int m    = lane & 15;
  const int b0   = blockIdx.x * BBLK;

  // --- register-resident W: kb 0..9 (B[k][col] = W[col][k])
  bf16x8 Wf[KB_REG][4];
#pragma unroll
  for (int kb = 0; kb < KB_REG; ++kb)
#pragma unroll
    for (int jt = 0; jt < 4; ++jt) {
      const int col = 64 * w + 16 * jt + m;
      const float4* p = reinterpret_cast<const float4*>(W + (size_t)col * H_ + 32 * kb + 8 * g);
      Wf[kb][jt] = pack8(p[0], p[1]);
    }

  // --- hbuf[0] = tanh(h0)
  for (int e = tid; e < BBLK * H_; e += SC_NW * 64) {
    const int r = e >> 9, k = e & (H_ - 1);
    hbuf[0][r][k] = f2bf(fast_tanh(h0[(size_t)(b0 + r) * H_ + k]));
  }

  // --- inp_cur for t=0: lane owns col = 64w+16g+m, rows 0..3
  const int mycol = 64 * w + 16 * g + m;
  float inp_cur[4];
#pragma unroll
  for (int r = 0; r < 4; ++r)
    inp_cur[r] = hid[((size_t)(b0 + r) * T_ + 0) * H_ + mycol];

  // --- stream: 6 groups (1 kb each) of 4 units; 2 rotating buffers
  const int sbase = (w * KB_STR * 4) * 64 + lane;   // + (G*4+jt)*64
  const bf16x8* SW = reinterpret_cast<const bf16x8*>(swbuf);
  bf16x8 s0[4], s1[4];
#pragma unroll
  for (int jt = 0; jt < 4; ++jt) s0[jt] = SW[sbase + (0 * 4 + jt) * 64];
#pragma unroll
  for (int jt = 0; jt < 4; ++jt) s1[jt] = SW[sbase + (1 * 4 + jt) * 64];

  __syncthreads();

#pragma clang loop unroll(disable)
  for (int t = 0; t < T_; ++t) {
    const int cur = t & 1, nxt = cur ^ 1;

    // opaque copy of stream base: blocks LICM/CSE of the loop-invariant W loads
    uintptr_t swo_u = (uintptr_t)SW;
    asm volatile("" : "+s"(swo_u));
    const bf16x8* SWo = (const bf16x8*)swo_u;

    // inp prefetch for t+1
    float inp_nxt[4] = {0.f, 0.f, 0.f, 0.f};
    if (t + 1 < T_) {
#pragma unroll
      for (int r = 0; r < 4; ++r)
        inp_nxt[r] = hid[((size_t)(b0 + r) * T_ + (t + 1)) * H_ + mycol];
    }

    const short* hr = &hbuf[cur][m & 3][0];
    f32x4 acc[4];
#pragma unroll
    for (int jt = 0; jt < 4; ++jt) acc[jt] = (f32x4){0.f, 0.f, 0.f, 0.f};

    // interleaved: reg kbs in pairs, streamed kbs consumed + group reloaded
#pragma unroll
    for (int ph = 0; ph < 5; ++ph) {
      // reg kb 2ph, 2ph+1
#pragma unroll
      for (int kk = 0; kk < 2; ++kk) {
        const int kb = 2 * ph + kk;
        const bf16x8 a = *reinterpret_cast<const bf16x8*>(hr + 32 * kb + 8 * g);
#pragma unroll
        for (int jt = 0; jt < 4; ++jt)
          acc[jt] = __builtin_amdgcn_mfma_f32_16x16x32_bf16(a, Wf[kb][jt], acc[jt], 0, 0, 0);
      }
      // streamed kb 10+ph (alternating buffer), reload with group ph+2
      if (ph < 4) {
        const bf16x8 a = *reinterpret_cast<const bf16x8*>(hr + 32 * (KB_REG + ph) + 8 * g);
        if ((ph & 1) == 0) {
#pragma unroll
          for (int jt = 0; jt < 4; ++jt)
            acc[jt] = __builtin_amdgcn_mfma_f32_16x16x32_bf16(a, s0[jt], acc[jt], 0, 0, 0);
#pragma unroll
          for (int jt = 0; jt < 4; ++jt) s0[jt] = SWo[sbase + ((ph + 2) * 4 + jt) * 64];
        } else {
#pragma unroll
          for (int jt = 0; jt < 4; ++jt)
            acc[jt] = __builtin_amdgcn_mfma_f32_16x16x32_bf16(a, s1[jt], acc[jt], 0, 0, 0);
#pragma unroll
          for (int jt = 0; jt < 4; ++jt) s1[jt] = SWo[sbase + ((ph + 2) * 4 + jt) * 64];
        }
      }
    }
    // streamed kb 14 (s0), kb 15 (s1); then pre-issue G0,G1 for next step
    {
      const bf16x8 a = *reinterpret_cast<const bf16x8*>(hr + 32 * 14 + 8 * g);
#pragma unroll
      for (int jt = 0; jt < 4; ++jt)
        acc[jt] = __builtin_amdgcn_mfma_f32_16x16x32_bf16(a, s0[jt], acc[jt], 0, 0, 0);
    }
    {
      const bf16x8 a = *reinterpret_cast<const bf16x8*>(hr + 32 * 15 + 8 * g);
#pragma unroll
      for (int jt = 0; jt < 4; ++jt)
        acc[jt] = __builtin_amdgcn_mfma_f32_16x16x32_bf16(a, s1[jt], acc[jt], 0, 0, 0);
    }
#pragma unroll
    for (int jt = 0; jt < 4; ++jt) s0[jt] = SWo[sbase + (0 * 4 + jt) * 64];
#pragma unroll
    for (int jt = 0; jt < 4; ++jt) s1[jt] = SWo[sbase + (1 * 4 + jt) * 64];

    // epilogue: lane picks acc[jt=g]; rows r=0..3, col = mycol
#pragma unroll
    for (int r = 0; r < 4; ++r) {
      float v = acc[0][r];
      v = (g == 1) ? acc[1][r] : v;
      v = (g == 2) ? acc[2][r] : v;
      v = (g == 3) ? acc[3][r] : v;
      v += inp_cur[r];
      hid[((size_t)(b0 + r) * T_ + t) * H_ + mycol] = v;
      hbuf[nxt][r][mycol] = f2bf(fast_tanh(v));
    }
#pragma unroll
    for (int r = 0; r < 4; ++r) inp_cur[r] = inp_nxt[r];

    // drain LDS only; vmcnt stays in flight (hid stores, inp/stream loads)
    asm volatile("s_waitcnt lgkmcnt(0)" ::: "memory");
    __builtin_amdgcn_s_barrier();
    asm volatile("" ::: "memory");
  }
}

// ---------------------------------------------------------------------------
// out = hidden @ W_out^T : memory-bound [BT,512]x[512,64] MFMA GEMM.
// ---------------------------------------------------------------------------
#define OP_BLOCKS 1024
#define OP_WAVES  8
__global__ __launch_bounds__(OP_WAVES * 64, 2) void out_proj(
    const float* __restrict__ hid, const float* __restrict__ Wout,
    float* __restrict__ out)
{
  __shared__ __align__(16) short ws[16][NOUT_][32];   // 64 KB

  const int tid  = threadIdx.x;
  const int lane = tid & 63;
  const int w    = tid >> 6;
  const int g    = lane >> 4;
  const int m    = lane & 15;

#pragma unroll
  for (int i = 0; i < 8; ++i) {
    const int c   = tid + OP_WAVES * 64 * i;
    const int kb  = c >> 8;
    const int col = (c >> 2) & 63;
    const int q   = (c & 3) * 8;
    const float4* p = reinterpret_cast<const float4*>(Wout + (size_t)col * H_ + 32 * kb + q);
    *reinterpret_cast<bf16x8*>(&ws[kb][col][q]) = pack8(p[0], p[1]);
  }
  __syncthreads();

  const int wave_id = blockIdx.x * OP_WAVES + w;
  const int NWAVES  = OP_BLOCKS * OP_WAVES;
  const int NTILES  = (B_ * T_) / 16;

  for (int tile = wave_id; tile < NTILES; tile += NWAVES) {
    const size_t row0 = (size_t)tile * 16;
    f32x4 acc[4];
    {
      const float4* p = reinterpret_cast<const float4*>(hid + (row0 + m) * H_ + 8 * g);
      const bf16x8 a = pack8(p[0], p[1]);
      const f32x4 zero = {0.f, 0.f, 0.f, 0.f};
#pragma unroll
      for (int jt = 0; jt < 4; ++jt) {
        const bf16x8 b = *reinterpret_cast<const bf16x8*>(&ws[0][16 * jt + m][8 * g]);
        acc[jt] = __builtin_amdgcn_mfma_f32_16x16x32_bf16(a, b, zero, 0, 0, 0);
      }
    }
#pragma unroll
    for (int kb = 1; kb < 16; ++kb) {
      const float4* p = reinterpret_cast<const float4*>(hid + (row0 + m) * H_ + 32 * kb + 8 * g);
      const bf16x8 a = pack8(p[0], p[1]);
#pragma unroll
      for (int jt = 0; jt < 4; ++jt) {
        const bf16x8 b = *reinterpret_cast<const bf16x8*>(&ws[kb][16 * jt + m][8 * g]);
        acc[jt] = __builtin_amdgcn_mfma_f32_16x16x32_bf16(a, b, acc[jt], 0, 0, 0);
      }
    }
#pragma unroll
    for (int jt = 0; jt < 4; ++jt)
#pragma unroll
      for (int r = 0; r < 4; ++r)
        out[(row0 + 4 * g + r) * NOUT_ + 16 * jt + m] = acc[jt][r];
  }
}

extern "C" void kernel_launch(void* const* d_in, const int* in_sizes, int n_in,
                              void* d_out, int out_size, void* d_ws, size_t ws_size,
                              hipStream_t stream) {
  const float* X    = (const float*)d_in[0];
  const float* h0   = (const float*)d_in[1];
  const float* W    = (const float*)d_in[2];
  const float* Win  = (const float*)d_in[3];
  const float* Wout = (const float*)d_in[4];

  float* out = (float*)d_out;                                   // [B,T,64]
  float* hid = (float*)d_out + (size_t)B_ * T_ * NOUT_;         // [B,T,512] (inp, then h)

  // streamed-W scratch (192 KB) at the tail of the out region; out_proj
  // overwrites it afterwards, so this is scratch-safe within one launch.
  const size_t out_elems = (size_t)B_ * T_ * NOUT_;
  short* sw = (short*)((float*)d_out + out_elems) - (size_t)SW_CHUNKS * 8;

  wprep<<<dim3(SW_CHUNKS / 512), dim3(512), 0, stream>>>(W, sw);
  xproj<<<dim3(XP_BLOCKS), dim3(512), 0, stream>>>(X, Win, hid);
  rnn_scan<<<dim3(B_ / BBLK), dim3(SC_NW * 64), 0, stream>>>(h0, W, hid, sw);
  out_proj<<<dim3(OP_BLOCKS), dim3(OP_WAVES * 64), 0, stream>>>(hid, Wout, out);
}

// Round 9
// 2855.267 us; speedup vs baseline: 2.1690x; 1.0243x over previous
//
#include <hip/hip_runtime.h>
#include <stdint.h>

#define B_    256
#define T_    1024
#define H_    512
#define NIN_  64
#define NOUT_ 64

// rnn_scan: 64 blocks x 8 waves (2 waves/SIMD, 256 unified regs/wave).
// Wave owns 64 cols (jt 0..3). W per wave:
//   kb 0..7  : AGPR via asm MFMA "a" operands (32 units = 128 AGPRs)
//   kb 8..11 : streamed from L2 each step (16 units, 2 rotating 4-unit bufs)
//   kb 12..15: LDS (16 units/wave, 128 KB/CU, per-lane-linear b128)
#define SC_NW   8
#define BBLK    4
#define HROW    528      // hbuf row stride in shorts (1056B -> 8-bank shift/row)
#define KB_AG   8
#define KB_ST   4        // kb 8..11 streamed
#define KB_LD   4        // kb 12..15 in LDS
#define LD_U    (KB_LD * 4)                    // 16 LDS units per wave
#define SW_CHUNKS (SC_NW * KB_ST * 4 * 64)     // 8192 chunks of 16B = 128 KB

typedef __attribute__((ext_vector_type(8))) short bf16x8;
typedef __attribute__((ext_vector_type(4))) float f32x4;

__device__ __forceinline__ short f2bf(float f) {
  uint32_t u = __float_as_uint(f);
  uint32_t r = (u + 0x7FFFu + ((u >> 16) & 1u)) >> 16;
  return (short)(r & 0xFFFFu);
}

__device__ __forceinline__ bf16x8 pack8(float4 lo, float4 hi) {
  bf16x8 s;
  s[0] = f2bf(lo.x); s[1] = f2bf(lo.y); s[2] = f2bf(lo.z); s[3] = f2bf(lo.w);
  s[4] = f2bf(hi.x); s[5] = f2bf(hi.y); s[6] = f2bf(hi.z); s[7] = f2bf(hi.w);
  return s;
}

__device__ __forceinline__ float fast_tanh(float x) {
  float e = __expf(2.0f * x);
  return 1.0f - __fdividef(2.0f, e + 1.0f);
}

// 4 MFMAs (shared A, B pinned in AGPR) in ONE asm block.
// Trailing s_nop 7 closes the WAR window on the shared A VGPRs (a later
// ds_read may write them; the hazard recognizer can't see inside asm).
// acc in/out via MFMA same-D chaining (architecturally 0 wait states).
__device__ __forceinline__ void mfma4_agpr(
    f32x4& d0, f32x4& d1, f32x4& d2, f32x4& d3, bf16x8 a,
    const bf16x8& b0, const bf16x8& b1, const bf16x8& b2, const bf16x8& b3) {
  asm volatile(
      "v_mfma_f32_16x16x32_bf16 %0, %4, %5, %0\n\t"
      "v_mfma_f32_16x16x32_bf16 %1, %4, %6, %1\n\t"
      "v_mfma_f32_16x16x32_bf16 %2, %4, %7, %2\n\t"
      "v_mfma_f32_16x16x32_bf16 %3, %4, %8, %3\n\t"
      "s_nop 7"
      : "+v"(d0), "+v"(d1), "+v"(d2), "+v"(d3)
      : "v"(a), "a"(b0), "a"(b1), "a"(b2), "a"(b3));
}

// ---------------------------------------------------------------------------
// wprep: pre-convert streamed W (kb 8..11) into per-lane bf16 fragment order.
// chunk c = ((w*4+G)*4 + jt)*64 + lane  ->  16 bytes at sw[c*8].
// ---------------------------------------------------------------------------
__global__ __launch_bounds__(512) void wprep(
    const float* __restrict__ W, short* __restrict__ sw)
{
  const int c = blockIdx.x * 512 + threadIdx.x;
  if (c >= SW_CHUNKS) return;
  const int lane = c & 63;
  const int u    = c >> 6;         // (w*4+G)*4 + jt
  const int jt   = u & 3;
  const int gw   = u >> 2;         // w*4 + G
  const int G    = gw & 3;
  const int w    = gw >> 2;
  const int col  = 64 * w + 16 * jt + (lane & 15);
  const int k0   = 32 * (KB_AG + G) + (lane >> 4) * 8;
  const float4* p = reinterpret_cast<const float4*>(W + (size_t)col * H_ + k0);
  *reinterpret_cast<bf16x8*>(sw + (size_t)c * 8) = pack8(p[0], p[1]);
}

// ---------------------------------------------------------------------------
// xproj: inp[b,t,h] = X[b,t,:] @ Win[h,:]  (f32, written into hid region)
// ---------------------------------------------------------------------------
#define XP_BLOCKS 512
__global__ __launch_bounds__(512, 2) void xproj(
    const float* __restrict__ X, const float* __restrict__ Win,
    float* __restrict__ inp)
{
  const int tid  = threadIdx.x;
  const int lane = tid & 63;
  const int w    = tid >> 6;
  const int g    = lane >> 4;
  const int m    = lane & 15;

  bf16x8 Bf[2][4];
#pragma unroll
  for (int kb = 0; kb < 2; ++kb)
#pragma unroll
    for (int jt = 0; jt < 4; ++jt) {
      const int j = 64 * w + 16 * jt + m;
      const float4* p = reinterpret_cast<const float4*>(Win + (size_t)j * NIN_ + 32 * kb + 8 * g);
      Bf[kb][jt] = pack8(p[0], p[1]);
    }

  const int NTILES = (B_ * T_) / 16;
  const f32x4 zero = {0.f, 0.f, 0.f, 0.f};

  for (int tile = blockIdx.x; tile < NTILES; tile += XP_BLOCKS) {
    const size_t row0 = (size_t)tile * 16;
    f32x4 acc[4];
    {
      const float4* p = reinterpret_cast<const float4*>(X + (row0 + m) * NIN_ + 8 * g);
      const bf16x8 a = pack8(p[0], p[1]);
#pragma unroll
      for (int jt = 0; jt < 4; ++jt)
        acc[jt] = __builtin_amdgcn_mfma_f32_16x16x32_bf16(a, Bf[0][jt], zero, 0, 0, 0);
    }
    {
      const float4* p = reinterpret_cast<const float4*>(X + (row0 + m) * NIN_ + 32 + 8 * g);
      const bf16x8 a = pack8(p[0], p[1]);
#pragma unroll
      for (int jt = 0; jt < 4; ++jt)
        acc[jt] = __builtin_amdgcn_mfma_f32_16x16x32_bf16(a, Bf[1][jt], acc[jt], 0, 0, 0);
    }
#pragma unroll
    for (int jt = 0; jt < 4; ++jt)
#pragma unroll
      for (int r = 0; r < 4; ++r)
        inp[(row0 + 4 * g + r) * H_ + 64 * w + 16 * jt + m] = acc[jt][r];
  }
}

// ---------------------------------------------------------------------------
// rnn_scan
// ---------------------------------------------------------------------------
__global__
__attribute__((amdgpu_flat_work_group_size(512, 512), amdgpu_waves_per_eu(2, 2)))
void rnn_scan(
    const float* __restrict__ h0, const float* __restrict__ W,
    float* __restrict__ hid, const short* __restrict__ swbuf)
{
  __shared__ __align__(16) short wlds[SC_NW * LD_U * 64 * 8];   // 128 KB: kb 12..15
  __shared__ __align__(16) short hbuf[2][BBLK][HROW];           // 8.4 KB

  const int tid  = threadIdx.x;
  const int lane = tid & 63;
  const int w    = tid >> 6;    // wave 0..7
  const int g    = lane >> 4;
  const int m    = lane & 15;
  const int b0   = blockIdx.x * BBLK;

  // launder pointers: loads from these can't be rematerialized from W directly
  const float* Wo = W;
  asm volatile("" : "+s"(Wo));
  const short* SWb = swbuf;
  asm volatile("" : "+s"(SWb));

  // --- AGPR-resident W: kb 0..7 (B[k][col] = W[col][k]); pinned by asm "a" use
  bf16x8 Wa[KB_AG][4];
#pragma unroll
  for (int kb = 0; kb < KB_AG; ++kb)
#pragma unroll
    for (int jt = 0; jt < 4; ++jt) {
      const int col = 64 * w + 16 * jt + m;
      const float4* p = reinterpret_cast<const float4*>(Wo + (size_t)col * H_ + 32 * kb + 8 * g);
      Wa[kb][jt] = pack8(p[0], p[1]);
    }

  // --- LDS-resident W: kb 12..15; unit u = (kb-12)*4+jt per wave ww
#pragma unroll
  for (int i = 0; i < 16; ++i) {
    const int c  = tid + 512 * i;          // < 8192 chunks of 8 shorts
    const int l  = c & 63;
    const int u  = (c >> 6) & 15;
    const int ww = c >> 10;
    const int kb = 12 + (u >> 2);
    const int jt = u & 3;
    const int col = 64 * ww + 16 * jt + (l & 15);
    const int k0  = 32 * kb + (l >> 4) * 8;
    const float4* p = reinterpret_cast<const float4*>(Wo + (size_t)col * H_ + k0);
    *reinterpret_cast<bf16x8*>(&wlds[((size_t)(ww * LD_U + u) * 64 + l) * 8]) = pack8(p[0], p[1]);
  }

  // --- hbuf[0] = tanh(h0)
  for (int e = tid; e < BBLK * H_; e += SC_NW * 64) {
    const int r = e >> 9, k = e & (H_ - 1);
    hbuf[0][r][k] = f2bf(fast_tanh(h0[(size_t)(b0 + r) * H_ + k]));
  }

  // --- inp_cur for t=0: lane owns col = 64w+16g+m, rows 0..3
  const int mycol = 64 * w + 16 * g + m;
  float inp_cur[4];
#pragma unroll
  for (int r = 0; r < 4; ++r)
    inp_cur[r] = hid[((size_t)(b0 + r) * T_ + 0) * H_ + mycol];

  // --- stream: groups G0..G3 = kb 8..11, 2 rotating buffers
  const int sbase = (w * KB_ST * 4) * 64 + lane;   // + (G*4+jt)*64
  const bf16x8* SW = reinterpret_cast<const bf16x8*>(SWb);
  bf16x8 sb0[4], sb1[4];
#pragma unroll
  for (int jt = 0; jt < 4; ++jt) sb0[jt] = SW[sbase + (0 * 4 + jt) * 64];
#pragma unroll
  for (int jt = 0; jt < 4; ++jt) sb1[jt] = SW[sbase + (1 * 4 + jt) * 64];

  __syncthreads();

#pragma clang loop unroll(disable)
  for (int t = 0; t < T_; ++t) {
    const int cur = t & 1, nxt = cur ^ 1;

    // fresh opaque stream base each iteration (blocks CSE across steps)
    uintptr_t swo_u = (uintptr_t)SW;
    asm volatile("" : "+s"(swo_u));
    const bf16x8* SWo = (const bf16x8*)swo_u;

    // inp prefetch for t+1 (overlaps the whole MFMA phase)
    float inp_nxt[4] = {0.f, 0.f, 0.f, 0.f};
    if (t + 1 < T_) {
#pragma unroll
      for (int r = 0; r < 4; ++r)
        inp_nxt[r] = hid[((size_t)(b0 + r) * T_ + (t + 1)) * H_ + mycol];
    }

    const short* hr = &hbuf[cur][m & 3][0];
    f32x4 acc[4];

    // S0: streamed kb8 initializes acc (builtin, C = 0); reload sb0 <- kb10
    {
      const bf16x8 a = *reinterpret_cast<const bf16x8*>(hr + 32 * 8 + 8 * g);
      const f32x4 zero = {0.f, 0.f, 0.f, 0.f};
#pragma unroll
      for (int jt = 0; jt < 4; ++jt)
        acc[jt] = __builtin_amdgcn_mfma_f32_16x16x32_bf16(a, sb0[jt], zero, 0, 0, 0);
#pragma unroll
      for (int jt = 0; jt < 4; ++jt) sb0[jt] = SWo[sbase + (2 * 4 + jt) * 64];
    }

    // ASM tier: kb 0..7 from AGPRs (same-D chaining from the S0 builtins)
#pragma unroll
    for (int kb = 0; kb < KB_AG; ++kb) {
      const bf16x8 a = *reinterpret_cast<const bf16x8*>(hr + 32 * kb + 8 * g);
      mfma4_agpr(acc[0], acc[1], acc[2], acc[3], a,
                 Wa[kb][0], Wa[kb][1], Wa[kb][2], Wa[kb][3]);
    }

    // S1: streamed kb9 (builtin); reload sb1 <- kb11
    {
      const bf16x8 a = *reinterpret_cast<const bf16x8*>(hr + 32 * 9 + 8 * g);
#pragma unroll
      for (int jt = 0; jt < 4; ++jt)
        acc[jt] = __builtin_amdgcn_mfma_f32_16x16x32_bf16(a, sb1[jt], acc[jt], 0, 0, 0);
#pragma unroll
      for (int jt = 0; jt < 4; ++jt) sb1[jt] = SWo[sbase + (3 * 4 + jt) * 64];
    }

    // L0: LDS kb 12,13 (builtin)
#pragma unroll
    for (int kk = 0; kk < 2; ++kk) {
      const int kb = 12 + kk;
      const bf16x8 a = *reinterpret_cast<const bf16x8*>(hr + 32 * kb + 8 * g);
#pragma unroll
      for (int jt = 0; jt < 4; ++jt) {
        const bf16x8 b = *reinterpret_cast<const bf16x8*>(
            &wlds[((size_t)(w * LD_U + kk * 4 + jt) * 64 + lane) * 8]);
        acc[jt] = __builtin_amdgcn_mfma_f32_16x16x32_bf16(a, b, acc[jt], 0, 0, 0);
      }
    }

    // S2: streamed kb10 (builtin); reload sb0 <- kb8 (next step)
    {
      const bf16x8 a = *reinterpret_cast<const bf16x8*>(hr + 32 * 10 + 8 * g);
#pragma unroll
      for (int jt = 0; jt < 4; ++jt)
        acc[jt] = __builtin_amdgcn_mfma_f32_16x16x32_bf16(a, sb0[jt], acc[jt], 0, 0, 0);
#pragma unroll
      for (int jt = 0; jt < 4; ++jt) sb0[jt] = SWo[sbase + (0 * 4 + jt) * 64];
    }

    // L1: LDS kb 14,15 (builtin)
#pragma unroll
    for (int kk = 2; kk < 4; ++kk) {
      const int kb = 12 + kk;
      const bf16x8 a = *reinterpret_cast<const bf16x8*>(hr + 32 * kb + 8 * g);
#pragma unroll
      for (int jt = 0; jt < 4; ++jt) {
        const bf16x8 b = *reinterpret_cast<const bf16x8*>(
            &wlds[((size_t)(w * LD_U + kk * 4 + jt) * 64 + lane) * 8]);
        acc[jt] = __builtin_amdgcn_mfma_f32_16x16x32_bf16(a, b, acc[jt], 0, 0, 0);
      }
    }

    // S3: streamed kb11 (builtin, LAST acc writer); reload sb1 <- kb9
    {
      const bf16x8 a = *reinterpret_cast<const bf16x8*>(hr + 32 * 11 + 8 * g);
#pragma unroll
      for (int jt = 0; jt < 4; ++jt)
        acc[jt] = __builtin_amdgcn_mfma_f32_16x16x32_bf16(a, sb1[jt], acc[jt], 0, 0, 0);
#pragma unroll
      for (int jt = 0; jt < 4; ++jt) sb1[jt] = SWo[sbase + (1 * 4 + jt) * 64];
    }

    // epilogue: lane picks acc[jt=g]; rows r=0..3, col = mycol
#pragma unroll
    for (int r = 0; r < 4; ++r) {
      float v = acc[0][r];
      v = (g == 1) ? acc[1][r] : v;
      v = (g == 2) ? acc[2][r] : v;
      v = (g == 3) ? acc[3][r] : v;
      v += inp_cur[r];
      hid[((size_t)(b0 + r) * T_ + t) * H_ + mycol] = v;
      hbuf[nxt][r][mycol] = f2bf(fast_tanh(v));
    }
#pragma unroll
    for (int r = 0; r < 4; ++r) inp_cur[r] = inp_nxt[r];

    // drain LDS only; vmcnt stays in flight (hid stores, inp/stream loads)
    asm volatile("s_waitcnt lgkmcnt(0)" ::: "memory");
    __builtin_amdgcn_s_barrier();
    asm volatile("" ::: "memory");
  }
}

// ---------------------------------------------------------------------------
// out = hidden @ W_out^T : memory-bound [BT,512]x[512,64] MFMA GEMM.
// ---------------------------------------------------------------------------
#define OP_BLOCKS 1024
#define OP_WAVES  8
__global__ __launch_bounds__(OP_WAVES * 64, 2) void out_proj(
    const float* __restrict__ hid, const float* __restrict__ Wout,
    float* __restrict__ out)
{
  __shared__ __align__(16) short ws[16][NOUT_][32];   // 64 KB

  const int tid  = threadIdx.x;
  const int lane = tid & 63;
  const int w    = tid >> 6;
  const int g    = lane >> 4;
  const int m    = lane & 15;

#pragma unroll
  for (int i = 0; i < 8; ++i) {
    const int c   = tid + OP_WAVES * 64 * i;
    const int kb  = c >> 8;
    const int col = (c >> 2) & 63;
    const int q   = (c & 3) * 8;
    const float4* p = reinterpret_cast<const float4*>(Wout + (size_t)col * H_ + 32 * kb + q);
    *reinterpret_cast<bf16x8*>(&ws[kb][col][q]) = pack8(p[0], p[1]);
  }
  __syncthreads();

  const int wave_id = blockIdx.x * OP_WAVES + w;
  const int NWAVES  = OP_BLOCKS * OP_WAVES;
  const int NTILES  = (B_ * T_) / 16;

  for (int tile = wave_id; tile < NTILES; tile += NWAVES) {
    const size_t row0 = (size_t)tile * 16;
    f32x4 acc[4];
    {
      const float4* p = reinterpret_cast<const float4*>(hid + (row0 + m) * H_ + 8 * g);
      const bf16x8 a = pack8(p[0], p[1]);
      const f32x4 zero = {0.f, 0.f, 0.f, 0.f};
#pragma unroll
      for (int jt = 0; jt < 4; ++jt) {
        const bf16x8 b = *reinterpret_cast<const bf16x8*>(&ws[0][16 * jt + m][8 * g]);
        acc[jt] = __builtin_amdgcn_mfma_f32_16x16x32_bf16(a, b, zero, 0, 0, 0);
      }
    }
#pragma unroll
    for (int kb = 1; kb < 16; ++kb) {
      const float4* p = reinterpret_cast<const float4*>(hid + (row0 + m) * H_ + 32 * kb + 8 * g);
      const bf16x8 a = pack8(p[0], p[1]);
#pragma unroll
      for (int jt = 0; jt < 4; ++jt) {
        const bf16x8 b = *reinterpret_cast<const bf16x8*>(&ws[kb][16 * jt + m][8 * g]);
        acc[jt] = __builtin_amdgcn_mfma_f32_16x16x32_bf16(a, b, acc[jt], 0, 0, 0);
      }
    }
#pragma unroll
    for (int jt = 0; jt < 4; ++jt)
#pragma unroll
      for (int r = 0; r < 4; ++r)
        out[(row0 + 4 * g + r) * NOUT_ + 16 * jt + m] = acc[jt][r];
  }
}

extern "C" void kernel_launch(void* const* d_in, const int* in_sizes, int n_in,
                              void* d_out, int out_size, void* d_ws, size_t ws_size,
                              hipStream_t stream) {
  const float* X    = (const float*)d_in[0];
  const float* h0   = (const float*)d_in[1];
  const float* W    = (const float*)d_in[2];
  const float* Win  = (const float*)d_in[3];
  const float* Wout = (const float*)d_in[4];

  float* out = (float*)d_out;                                   // [B,T,64]
  float* hid = (float*)d_out + (size_t)B_ * T_ * NOUT_;         // [B,T,512] (inp, then h)

  // streamed-W scratch (128 KB) at the tail of the out region; out_proj
  // overwrites it afterwards, so this is scratch-safe within one launch.
  const size_t out_elems = (size_t)B_ * T_ * NOUT_;
  short* sw = (short*)((float*)d_out + out_elems) - (size_t)SW_CHUNKS * 8;

  wprep<<<dim3(SW_CHUNKS / 512), dim3(512), 0, stream>>>(W, sw);
  xproj<<<dim3(XP_BLOCKS), dim3(512), 0, stream>>>(X, Win, hid);
  rnn_scan<<<dim3(B_ / BBLK), dim3(SC_NW * 64), 0, stream>>>(h0, W, hid, sw);
  out_proj<<<dim3(OP_BLOCKS), dim3(OP_WAVES * 64), 0, stream>>>(hid, Wout, out);
}